// Round 5
// baseline (165.355 us; speedup 1.0000x reference)
//
#include <hip/hip_runtime.h>

constexpr int B_DIM = 256, T_DIM = 8192;
constexpr long long GATE_N = (long long)B_DIM * 2 * T_DIM;   // 4,194,304
constexpr long long EXT_N  = GATE_N * 5;                     // 20,971,520

// One tiny block: fold breath@temple -> w[0..4] (main), w[5..9] (mirror), w[10]=mode.
__global__ void temple_setup(const float* __restrict__ x, const float* __restrict__ temple,
                             const float* __restrict__ breath,
                             float* __restrict__ out, double* __restrict__ w) {
    if (threadIdx.x != 0) return;
    double s = 0.0;
    for (int d = 0; d < 5; ++d) s += (double)x[d];
    s = s / 5.0;
    double seed  = s - floor(s);
    double chaos = 3.5699456 * seed * (1.0 - seed);
    int mode = (chaos > 0.7) ? 0 : ((chaos > 0.4) ? 1 : 2);
    for (int d = 0; d < 5; ++d) {
        double a = 0.0, c = 0.0;
        for (int r = 0; r < 4; ++r) {
            double tv = (double)temple[r * 5 + d];
            a += (double)breath[r]     * tv;   // breath_main = breath[0:4]
            c += (double)breath[r + 1] * tv;   // breath_mirror = breath[1:5]
        }
        w[d] = a; w[5 + d] = c;
    }
    w[10] = (double)mode;
    out[GATE_N + EXT_N] = (float)mode;
}

// Pure-streaming extended_x writer. Half-row = 8192 items * 5 f = 10240 float4;
// 40 blocks per b-row, one main float4 + one mirror float4 per thread.
__global__ __launch_bounds__(256) void temple_copy(const float* __restrict__ x,
                                                   const double* __restrict__ w,
                                                   float* __restrict__ out) {
    const int b = blockIdx.x / 40;
    const int j = (blockIdx.x - b * 40) * 256 + threadIdx.x;   // [0, 10240) float4 in half-row
    const int mode = (int)w[10];                                // uniform scalar load

    const float4 v = ((const float4*)x)[(long long)b * 10240 + j];
    float4* dst = (float4*)(out + GATE_N) + (long long)b * 20480;
    dst[j] = v;                                                 // main half: pure copy

    if (mode == 0) {
        dst[10240 + j] = make_float4(9.f - v.x, 9.f - v.y, 9.f - v.z, 9.f - v.w);
    } else if (mode == 2) {
        dst[10240 + j] = v;
    } else {
        // flip along t: dest row-local float fl -> src float 40955 - fl + 2*(fl%5).
        // Consecutive lanes gather from a contiguous descending window: L1/L3-hot.
        const float* __restrict__ xr = x + (long long)b * 40960;
        float vv[4];
#pragma unroll
        for (int c = 0; c < 4; ++c) {
            const int fl = j * 4 + c;
            const int d  = fl % 5;
            vv[c] = xr[40955 - fl + 2 * d];
        }
        dst[10240 + j] = make_float4(vv[0], vv[1], vv[2], vv[3]);
    }
}

// Scan kernel: 1 item/thread, dual interleaved f64 chains (bit-identical step math),
// f32 sum/sumsq epilogue (saves the h[10] register arrays).
__global__ __launch_bounds__(256) void temple_gate(const float* __restrict__ x,
                                                   const double* __restrict__ w,
                                                   float* __restrict__ out) {
    const long long tid = (long long)blockIdx.x * 256 + threadIdx.x;
    const int b = (int)(tid >> 13);
    const int t = (int)(tid & (T_DIM - 1));
    const int mode = (int)w[10];
    const long long rowBase = (long long)b * (2 * T_DIM);

    const float* __restrict__ xi = x + ((long long)b * T_DIM + t) * 5;
    const float x0 = xi[0], x1 = xi[1], x2 = xi[2], x3 = xi[3], x4 = xi[4];

    const double wa0 = w[0], wa1 = w[1], wa2 = w[2], wa3 = w[3], wa4 = w[4];
    const double wb0 = w[5], wb1 = w[6], wb2 = w[7], wb3 = w[8], wb4 = w[9];
    double a0 = x0, a1 = x1, a2 = x2, a3 = x3, a4 = x4;
    double b0, b1, b2, b3, b4;
    if (mode == 0) { b0 = 9.0 - a0; b1 = 9.0 - a1; b2 = 9.0 - a2; b3 = 9.0 - a3; b4 = 9.0 - a4; }
    else           { b0 = a0; b1 = a1; b2 = a2; b3 = a3; b4 = a4; }

    float sumA = 0.f, sqA = 0.f, sumB = 0.f, sqB = 0.f;
#pragma unroll
    for (int s = 0; s < 10; ++s) {
        double ra = a0 * wa0;
        ra = fma(a1, wa1, ra); ra = fma(a2, wa2, ra); ra = fma(a3, wa3, ra); ra = fma(a4, wa4, ra);
        double rb = b0 * wb0;
        rb = fma(b1, wb1, rb); rb = fma(b2, wb2, rb); rb = fma(b3, wb3, rb); rb = fma(b4, wb4, rb);
        const float fa = (float)ra, fb = (float)rb;
        sumA += fa; sqA = fmaf(fa, fa, sqA);
        sumB += fb; sqB = fmaf(fb, fb, sqB);
        double qa = floor(ra * 0.1), ma = fma(qa, -10.0, ra);
        ma = (ma < 0.0) ? ma + 10.0 : ma;  ma = (ma >= 10.0) ? ma - 10.0 : ma;
        double qb = floor(rb * 0.1), mb = fma(qb, -10.0, rb);
        mb = (mb < 0.0) ? mb + 10.0 : mb;  mb = (mb >= 10.0) ? mb - 10.0 : mb;
        a4 = a3; a3 = a2; a2 = a1; a1 = a0; a0 = ma;
        b4 = b3; b3 = b2; b2 = b1; b1 = b0; b0 = mb;
    }
    // var = (sumsq - sum^2/10) / 9  (ddof=1); f32 cancellation error ~1e-5, harmless.
    const float meanA = sumA * 0.1f, meanB = sumB * 0.1f;
    float varA = fmaf(-meanA, sumA, sqA) * (1.0f / 9.0f);
    float varB = fmaf(-meanB, sumB, sqB) * (1.0f / 9.0f);
    varA = varA > 0.f ? varA : 0.f;
    varB = varB > 0.f ? varB : 0.f;
    const float gm = 1.0f / (1.0f + sqrtf(varA));
    const float gx = 1.0f / (1.0f + sqrtf(varB));

    out[rowBase + t] = gm;
    if (mode == 1) out[rowBase + 2 * T_DIM - 1 - t] = gx;
    else           out[rowBase + T_DIM + t] = gx;
}

extern "C" void kernel_launch(void* const* d_in, const int* in_sizes, int n_in,
                              void* d_out, int out_size, void* d_ws, size_t ws_size,
                              hipStream_t stream) {
    const float* x      = (const float*)d_in[0];   // (256, 8192, 5) f32
    const float* temple = (const float*)d_in[1];   // (4, 5) f32
    const float* breath = (const float*)d_in[2];   // (5,) f32
    float* out = (float*)d_out;                    // [gate | extended_x | mode_code]
    double* w  = (double*)d_ws;                    // 11 doubles

    temple_setup<<<1, 64, 0, stream>>>(x, temple, breath, out, w);
    temple_copy<<<B_DIM * 40, 256, 0, stream>>>(x, w, out);     // 10240 blocks
    temple_gate<<<(B_DIM * T_DIM) / 256, 256, 0, stream>>>(x, w, out);  // 8192 blocks
}